// Round 12
// baseline (102.617 us; speedup 1.0000x reference)
//
#include <hip/hip_runtime.h>
#include <stdint.h>

#define BN       16384
#define NTILES   256     // BN/64
#define NB       64      // norm buckets
#define NW       16      // waves in prep block
#define KOUT     16
#define MARGIN   0.01f   // certified slack >> max fp32 eval error (~4e-5)
#define PPT      16      // points/thread in prep (16384/1024)

typedef float v2f __attribute__((ext_vector_type(2)));
union F4 { float4 f4; v2f p[2]; float f[4]; };

// ---- workspace layout (bytes) ----
#define WS_TAB    0                        // float4[BN]   262144
#define WS_IDX    (WS_TAB + BN * 16)       // u32[BN]       65536
#define WS_BND    (WS_IDX + BN * 4)        // float2[NTILES] 2048

// sortable key of float bits (ascending uint == ascending float)
__device__ __forceinline__ unsigned key_u(unsigned u) {
    return u ^ ((unsigned)((int)u >> 31) | 0x80000000u);
}
__device__ __forceinline__ unsigned key2f_u(unsigned t) {
    return t ^ ((unsigned)((int)(~t) >> 31) | 0x80000000u);
}
__device__ __forceinline__ unsigned wshr1(unsigned v, unsigned oldv) {
    return (unsigned)__builtin_amdgcn_update_dpp((int)oldv, (int)v, 0x138 /*WAVE_SHR:1*/,
                                                 0xF, 0xF, false);
}
#define RL16(T) __uint_as_float((unsigned)__builtin_amdgcn_readlane(__float_as_int(T), 16))

// exact np-order squared norm: (x^2 + y^2) + z^2
__device__ __forceinline__ float sq_of(float gx, float gy, float gz) {
    return __fadd_rn(__fadd_rn(__fmul_rn(gx, gx), __fmul_rn(gy, gy)), __fmul_rn(gz, gz));
}
__device__ __forceinline__ int bucket_of(float sq) {
    const float rho = __fsqrt_rn(sq);
    int b = (int)(64.0f * (1.0f - rho * 0.2f));  // edges rho_b = 5*(1-b/64)
    return (b < 0) ? 0 : ((b > 63) ? 63 : b);
}

// Lexicographic (pair asc, idx asc) sorted insert -> scan-order independent.
#define DRAIN(m, p, jvec, T, J)                                                     \
    while (m) {                                                                     \
        const int b_ = (int)__builtin_ctzll(m);                                     \
        m &= m - 1;                                                                 \
        const float pc_ = __uint_as_float(                                          \
            (unsigned)__builtin_amdgcn_readlane(__float_as_int(p), b_));            \
        const unsigned jc_ = (unsigned)__builtin_amdgcn_readlane((int)(jvec), b_);  \
        const float Tup_ =                                                          \
            __uint_as_float(wshr1(__float_as_uint(T), 0xFF800000u /*-inf*/));       \
        const unsigned Jup_ = wshr1((J), 0u);                                       \
        const bool lt_ = (pc_ < Tup_) || ((pc_ == Tup_) && (jc_ < Jup_));           \
        const float Tn_ = lt_ ? Tup_ : pc_;                                         \
        const unsigned Jn_ = lt_ ? Jup_ : jc_;                                      \
        const bool sel_ = (pc_ < (T)) || ((pc_ == (T)) && (jc_ < (J)));             \
        (T) = sel_ ? Tn_ : (T);                                                     \
        (J) = sel_ ? Jn_ : (J);                                                     \
    }

// d2 = ((2*dot + nsq_q) + nsq_j) packed for 2 queries, bitwise == reference chain.
#define EVALC(c, d2)                                                                \
    asm("v_pk_mul_f32 %0, %1, %2 op_sel:[0,0] op_sel_hi:[0,1]"                      \
        : "=v"(d2) : "v"((c).p[0]), "v"(c0A));                                      \
    asm("v_pk_fma_f32 %0, %1, %2, %0 op_sel:[1,0,0] op_sel_hi:[1,1,1]"              \
        : "+v"(d2) : "v"((c).p[0]), "v"(c1A));                                      \
    asm("v_pk_fma_f32 %0, %1, %2, %0 op_sel:[0,0,0] op_sel_hi:[0,1,1]"              \
        : "+v"(d2) : "v"((c).p[1]), "v"(c2A));                                      \
    asm("v_pk_add_f32 %0, %0, %1" : "+v"(d2) : "v"(nsq01));                         \
    asm("v_pk_add_f32 %0, %0, %1 op_sel:[0,1] op_sel_hi:[1,1]"                      \
        : "+v"(d2) : "v"((c).p[1]));

#define TILE_AT(t)                                                                  \
    F4 c; c.f4 = tab[(t) * 64 + lane];                                              \
    const unsigned jvec = idxarr[(t) * 64 + lane];                                  \
    v2f d2; EVALC(c, d2)

#define PROCESS_LOADED()                                                            \
    do {                                                                            \
        uint64_t m0 = __ballot(d2[0] <= fF0);                                       \
        uint64_t m1 = __ballot(d2[1] <= fF1);                                       \
        if (m0 | m1) {                                                              \
            const float p0 = d2[0], p1 = d2[1];                                     \
            DRAIN(m0, p0, jvec, T0, J0)                                             \
            DRAIN(m1, p1, jvec, T1, J1)                                             \
            fF0 = RL16(T0); thr0 = __fsub_rn(-fF0, MARGIN);                         \
            fF1 = RL16(T1); thr1 = __fsub_rn(-fF1, MARGIN);                         \
        }                                                                           \
    } while (0)

// ---- fused single-block prep with per-wave histograms (R11, unchanged) ----
__global__ __launch_bounds__(1024) void k_prep(const float* __restrict__ x,
                                               float4* __restrict__ tab,
                                               unsigned* __restrict__ idxarr,
                                               float2* __restrict__ bnd) {
    __shared__ unsigned cnt[NW * 65];   // per-wave hist/cursors, +1 pad rotates banks
    __shared__ unsigned base[NB];
    __shared__ unsigned tmaxs[NTILES];
    const int tid  = threadIdx.x;
    const int wid  = tid >> 6;
    for (int i = tid; i < NW * 65; i += 1024) cnt[i] = 0u;
    if (tid < NTILES) tmaxs[tid] = 0u;
    __syncthreads();

    float px[PPT], py[PPT], pz[PPT], psq[PPT];
    int pb[PPT];
#pragma unroll
    for (int k = 0; k < PPT; ++k) {
        const int i = tid + k * 1024;  // coalesced across lanes
        const float gx = x[3 * i], gy = x[3 * i + 1], gz = x[3 * i + 2];
        const float sq = sq_of(gx, gy, gz);
        px[k] = gx; py[k] = gy; pz[k] = gz; psq[k] = sq;
        pb[k] = bucket_of(sq);
        atomicAdd(&cnt[wid * 65 + pb[k]], 1u);
    }
    __syncthreads();
    if (tid < NB) {
        unsigned s = 0;
#pragma unroll
        for (int w = 0; w < NW; ++w) s += cnt[w * 65 + tid];
        base[tid] = s;
    }
    __syncthreads();
    if (tid == 0) {
        unsigned s = 0;
        for (int b = 0; b < NB; ++b) { const unsigned t = base[b]; base[b] = s; s += t; }
    }
    __syncthreads();
    if (tid < NB) {
        unsigned s = base[tid];
#pragma unroll
        for (int w = 0; w < NW; ++w) {
            const unsigned t = cnt[w * 65 + tid];
            cnt[w * 65 + tid] = s;
            s += t;
        }
    }
    __syncthreads();
#pragma unroll
    for (int k = 0; k < PPT; ++k) {
        const int i = tid + k * 1024;
        const unsigned pos = atomicAdd(&cnt[wid * 65 + pb[k]], 1u);
        tab[pos] = make_float4(px[k], py[k], pz[k], -psq[k]);
        idxarr[pos] = (unsigned)i;
        atomicMax(&tmaxs[pos >> 6], __float_as_uint(psq[k]));  // sq>0: bits monotone
    }
    __syncthreads();
    for (int s = 1; s < NTILES; s <<= 1) {  // suffix max, log steps
        unsigned v = 0;
        if (tid < NTILES) {
            v = tmaxs[tid];
            if (tid + s < NTILES) { const unsigned w = tmaxs[tid + s]; v = (w > v) ? w : v; }
        }
        __syncthreads();
        if (tid < NTILES) tmaxs[tid] = v;
        __syncthreads();
    }
    if (tid < NTILES) {
        const float B = __uint_as_float(tmaxs[tid]);
        const float sqB_up = __uint_as_float(__float_as_uint(__fsqrt_rn(B)) + 2u);
        bnd[tid] = make_float2(B, sqB_up);
    }
}

// ---- main kernel: LDS-free seed (ballot binary search) + pipelined scan ----
__global__ __launch_bounds__(256) void knn_far_kernel(
    const float* __restrict__ x, const float4* __restrict__ tab,
    const unsigned* __restrict__ idxarr, const float2* __restrict__ bnd,
    float* __restrict__ out_d, float* __restrict__ out_i) {
    const int tid  = threadIdx.x;
    const int lane = tid & 63;
    const int wid  = tid >> 6;
    const int q0 = (blockIdx.x * 4 + wid) * 2;
    const int q1 = q0 + 1;

    const float a0 = x[3 * q0], a1 = x[3 * q0 + 1], a2 = x[3 * q0 + 2];
    const float b0 = x[3 * q1], b1 = x[3 * q1 + 1], b2 = x[3 * q1 + 2];
    const float sq0 = sq_of(a0, a1, a2), sq1 = sq_of(b0, b1, b2);
    const v2f nsq01 = {-sq0, -sq1};
    const v2f c0A = {2.0f * a0, 2.0f * b0};
    const v2f c1A = {2.0f * a1, 2.0f * b1};
    const v2f c2A = {2.0f * a2, 2.0f * b2};
    // upper-bounded 2*|q| for the certificate
    const float twor0 = 2.0f * __uint_as_float(__float_as_uint(__fsqrt_rn(sq0)) + 2u);
    const float twor1 = 2.0f * __uint_as_float(__float_as_uint(__fsqrt_rn(sq1)) + 2u);

    float T0 = __uint_as_float(0x7F800000u), T1 = T0;  // +inf sentinels
    unsigned J0 = 0u, J1 = 0u;
    float fF0, fF1, thr0, thr1;

    {   // tile 0: exact 17th-smallest key via ballot binary search (no LDS),
        // then drain through the normal filtered path (~17 inserts).
        F4 c; c.f4 = tab[lane];
        const unsigned jvec = idxarr[lane];
        v2f d2; EVALC(c, d2)
        const unsigned kk0 = key_u(__float_as_uint(d2[0]));
        const unsigned kk1 = key_u(__float_as_uint(d2[1]));
        unsigned lo0 = 0u, hi0 = 0xFFFFFFFFu;
        unsigned lo1 = 0u, hi1 = 0xFFFFFFFFu;
        for (int it = 0; it < 32; ++it) {  // both searches interleaved (ILP)
            const unsigned mid0 = lo0 + ((hi0 - lo0) >> 1);
            const unsigned mid1 = lo1 + ((hi1 - lo1) >> 1);
            const int n0 = __popcll(__ballot(kk0 <= mid0));
            const int n1 = __popcll(__ballot(kk1 <= mid1));
            if (n0 >= KOUT + 1) hi0 = mid0; else lo0 = mid0 + 1u;
            if (n1 >= KOUT + 1) hi1 = mid1; else lo1 = mid1 + 1u;
        }
        fF0 = __uint_as_float(key2f_u(lo0)); thr0 = __fsub_rn(-fF0, MARGIN);
        fF1 = __uint_as_float(key2f_u(lo1)); thr1 = __fsub_rn(-fF1, MARGIN);
        uint64_t m0 = __ballot(kk0 <= lo0);
        uint64_t m1 = __ballot(kk1 <= lo1);
        const float p0 = d2[0], p1 = d2[1];
        DRAIN(m0, p0, jvec, T0, J0)
        DRAIN(m1, p1, jvec, T1, J1)
    }
#pragma unroll
    for (int t = 1; t < 4; ++t) {  // rest of the seed region (top-256 norms)
        TILE_AT(t)
        PROCESS_LOADED();
    }

    // pipelined certified scan: prefetch t+1 while processing t
    F4 cp; cp.f4 = tab[4 * 64 + lane];
    unsigned jp = idxarr[4 * 64 + lane];
    float2 bdp = bnd[4];
    for (int t = 4; t < NTILES; ++t) {
        const float u0 = __builtin_fmaf(twor0, bdp.y, __fadd_rn(sq0, bdp.x));
        const float u1 = __builtin_fmaf(twor1, bdp.y, __fadd_rn(sq1, bdp.x));
        if (u0 < thr0 && u1 < thr1) break;  // certified: no future point can matter
        const int tn = (t + 1 < NTILES) ? (t + 1) : t;
        F4 c2; c2.f4 = tab[tn * 64 + lane];          // prefetch (speculative, safe)
        const unsigned j2 = idxarr[tn * 64 + lane];
        const float2 bd2 = bnd[tn];
        {
            v2f d2; EVALC(cp, d2)
            uint64_t m0 = __ballot(d2[0] <= fF0);
            uint64_t m1 = __ballot(d2[1] <= fF1);
            if (m0 | m1) {
                const float p0 = d2[0], p1 = d2[1];
                const unsigned jvv = jp;
                DRAIN(m0, p0, jvv, T0, J0)
                DRAIN(m1, p1, jvv, T1, J1)
                fF0 = RL16(T0); thr0 = __fsub_rn(-fF0, MARGIN);
                fF1 = RL16(T1); thr1 = __fsub_rn(-fF1, MARGIN);
            }
        }
        cp = c2; jp = j2; bdp = bd2;
    }

    if (lane >= 1 && lane <= KOUT) {  // ranks 1..16 (rank 0 dropped by reference)
        const int r = lane - 1;
        out_d[q0 * KOUT + r] = T0;
        out_i[q0 * KOUT + r] = (float)J0;
        out_d[q1 * KOUT + r] = T1;
        out_i[q1 * KOUT + r] = (float)J1;
    }
}

extern "C" void kernel_launch(void* const* d_in, const int* in_sizes, int n_in,
                              void* d_out, int out_size, void* d_ws, size_t ws_size,
                              hipStream_t stream) {
    const float* x = (const float*)d_in[0];
    char* ws = (char*)d_ws;
    float4*   tab    = (float4*)(ws + WS_TAB);
    unsigned* idxarr = (unsigned*)(ws + WS_IDX);
    float2*   bnd    = (float2*)(ws + WS_BND);
    float* out_d = (float*)d_out;
    float* out_i = out_d + (size_t)BN * KOUT;

    hipLaunchKernelGGL(k_prep, dim3(1), dim3(1024), 0, stream, x, tab, idxarr, bnd);
    hipLaunchKernelGGL(knn_far_kernel, dim3(BN / 8), dim3(256), 0, stream,
                       x, tab, idxarr, bnd, out_d, out_i);
}

// Round 13
// 82.857 us; speedup vs baseline: 1.2385x; 1.2385x over previous
//
#include <hip/hip_runtime.h>
#include <stdint.h>

#define BN       16384
#define NTILES   256     // BN/64
#define NB       64      // norm buckets
#define KOUT     16
#define MARGIN   0.01f   // certified slack >> max fp32 eval error (~4e-5)

typedef float v2f __attribute__((ext_vector_type(2)));
union F4 { float4 f4; v2f p[2]; float f[4]; };

// ---- workspace layout (bytes) ----
#define WS_TAB    0                         // float4[BN]    262144
#define WS_IDX    (WS_TAB + BN * 16)        // u32[BN]        65536
#define WS_BND    (WS_IDX + BN * 4)         // float2[NTILES]  2048
#define WS_HIST   (WS_BND + NTILES * 8)     // u32[64][NB]    16384
#define WS_HMAX   (WS_HIST + 64 * NB * 4)   // u32[64][NB]    16384
#define WS_CBASE  (WS_HMAX + 64 * NB * 4)   // u32[64][NB]    16384

// sortable key of float bits (ascending uint == ascending float)
__device__ __forceinline__ unsigned key_u(unsigned u) {
    return u ^ ((unsigned)((int)u >> 31) | 0x80000000u);
}
__device__ __forceinline__ unsigned wshr1(unsigned v, unsigned oldv) {
    return (unsigned)__builtin_amdgcn_update_dpp((int)oldv, (int)v, 0x138 /*WAVE_SHR:1*/,
                                                 0xF, 0xF, false);
}
#define RL16(T) __uint_as_float((unsigned)__builtin_amdgcn_readlane(__float_as_int(T), 16))

// exact np-order squared norm: (x^2 + y^2) + z^2
__device__ __forceinline__ float sq_of(float gx, float gy, float gz) {
    return __fadd_rn(__fadd_rn(__fmul_rn(gx, gx), __fmul_rn(gy, gy)), __fmul_rn(gz, gz));
}
__device__ __forceinline__ int bucket_of(float sq) {
    const float rho = __fsqrt_rn(sq);
    int b = (int)(64.0f * (1.0f - rho * 0.2f));  // edges rho_b = 5*(1-b/64)
    return (b < 0) ? 0 : ((b > 63) ? 63 : b);
}

// Lexicographic (pair asc, idx asc) sorted insert -> scan-order independent.
#define DRAIN(m, p, jvec, T, J)                                                     \
    while (m) {                                                                     \
        const int b_ = (int)__builtin_ctzll(m);                                     \
        m &= m - 1;                                                                 \
        const float pc_ = __uint_as_float(                                          \
            (unsigned)__builtin_amdgcn_readlane(__float_as_int(p), b_));            \
        const unsigned jc_ = (unsigned)__builtin_amdgcn_readlane((int)(jvec), b_);  \
        const float Tup_ =                                                          \
            __uint_as_float(wshr1(__float_as_uint(T), 0xFF800000u /*-inf*/));       \
        const unsigned Jup_ = wshr1((J), 0u);                                       \
        const bool lt_ = (pc_ < Tup_) || ((pc_ == Tup_) && (jc_ < Jup_));           \
        const float Tn_ = lt_ ? Tup_ : pc_;                                         \
        const unsigned Jn_ = lt_ ? Jup_ : jc_;                                      \
        const bool sel_ = (pc_ < (T)) || ((pc_ == (T)) && (jc_ < (J)));             \
        (T) = sel_ ? Tn_ : (T);                                                     \
        (J) = sel_ ? Jn_ : (J);                                                     \
    }

// d2 = ((2*dot + nsq_q) + nsq_j) packed for 2 queries, bitwise == reference chain.
#define EVALC(c, d2)                                                                \
    asm("v_pk_mul_f32 %0, %1, %2 op_sel:[0,0] op_sel_hi:[0,1]"                      \
        : "=v"(d2) : "v"((c).p[0]), "v"(c0A));                                      \
    asm("v_pk_fma_f32 %0, %1, %2, %0 op_sel:[1,0,0] op_sel_hi:[1,1,1]"              \
        : "+v"(d2) : "v"((c).p[0]), "v"(c1A));                                      \
    asm("v_pk_fma_f32 %0, %1, %2, %0 op_sel:[0,0,0] op_sel_hi:[0,1,1]"              \
        : "+v"(d2) : "v"((c).p[1]), "v"(c2A));                                      \
    asm("v_pk_add_f32 %0, %0, %1" : "+v"(d2) : "v"(nsq01));                         \
    asm("v_pk_add_f32 %0, %0, %1 op_sel:[0,1] op_sel_hi:[1,1]"                      \
        : "+v"(d2) : "v"((c).p[1]));

#define TILE_AT(t)                                                                  \
    F4 c; c.f4 = tab[(t) * 64 + lane];                                              \
    const unsigned jvec = idxarr[(t) * 64 + lane];                                  \
    v2f d2; EVALC(c, d2)

#define PROCESS_LOADED()                                                            \
    do {                                                                            \
        uint64_t m0 = __ballot(d2[0] <= fF0);                                       \
        uint64_t m1 = __ballot(d2[1] <= fF1);                                       \
        if (m0 | m1) {                                                              \
            const float p0 = d2[0], p1 = d2[1];                                     \
            DRAIN(m0, p0, jvec, T0, J0)                                             \
            DRAIN(m1, p1, jvec, T1, J1)                                             \
            fF0 = RL16(T0); thr0 = __fsub_rn(-fF0, MARGIN);                         \
            fF1 = RL16(T1); thr1 = __fsub_rn(-fF1, MARGIN);                         \
        }                                                                           \
    } while (0)

// Wave-parallel exact sort of 64 (p, j) pairs by (p asc, j asc) — R11 verbatim.
__device__ __forceinline__ void presort64(float p, unsigned j, int lane, double* sw,
                                          float& T, unsigned& J) {
    const double dm = (double)key_u(__float_as_uint(p)) * 16384.0 + (double)j;
    sw[lane] = dm;
    unsigned rank = 0;
    const char* sb = (const char*)sw;
    unsigned off = (unsigned)lane * 8u;
#pragma unroll 7
    for (int s = 1; s < 64; ++s) {
        off = (off + 8u) & 511u;
        const double dn = *(const double*)(sb + off);
        rank += (dn < dm) ? 1u : 0u;
    }
    sw[rank] = __longlong_as_double(
        (long long)(((unsigned long long)j << 32) | __float_as_uint(p)));
    const unsigned long long v = (unsigned long long)__double_as_longlong(sw[lane]);
    T = __uint_as_float((unsigned)(v & 0xFFFFFFFFull));
    J = (unsigned)(v >> 32);
}

// ---- prep 1: per-block histogram + per-bucket max norm (64 blocks, parallel) ----
__global__ __launch_bounds__(256) void k_hist(const float* __restrict__ x,
                                              unsigned* __restrict__ hist,
                                              unsigned* __restrict__ hmax) {
    __shared__ unsigned h[NB], m[NB];
    const int tid = threadIdx.x;
    if (tid < NB) { h[tid] = 0u; m[tid] = 0u; }
    __syncthreads();
    const int i = blockIdx.x * 256 + tid;
    const float sq = sq_of(x[3 * i], x[3 * i + 1], x[3 * i + 2]);
    const int b = bucket_of(sq);
    atomicAdd(&h[b], 1u);
    atomicMax(&m[b], __float_as_uint(sq));  // sq>0: float bits monotone
    __syncthreads();
    if (tid < NB) {
        hist[blockIdx.x * NB + tid] = h[tid];
        hmax[blockIdx.x * NB + tid] = m[tid];
    }
}

// ---- prep 2: bases, per-(block,bucket) cursors, per-tile bounds (1 block) ----
__global__ __launch_bounds__(256) void k_mid(const unsigned* __restrict__ hist,
                                             const unsigned* __restrict__ hmax,
                                             unsigned* __restrict__ cbase,
                                             float2* __restrict__ bnd) {
    __shared__ unsigned tot[NB], basev[NB + 1], sfx[NB];
    const int tid = threadIdx.x;
    if (tid < NB) {
        unsigned s = 0, mx = 0;
        for (int g = 0; g < 64; ++g) {
            s += hist[g * NB + tid];
            const unsigned w = hmax[g * NB + tid];
            mx = (w > mx) ? w : mx;
        }
        tot[tid] = s;
        sfx[tid] = mx;  // temporarily per-bucket max
    }
    __syncthreads();
    if (tid == 0) {
        unsigned s = 0;
        for (int b = 0; b < NB; ++b) { basev[b] = s; s += tot[b]; }
        basev[NB] = s;
        unsigned M = 0;
        for (int b = NB - 1; b >= 0; --b) { const unsigned w = sfx[b]; M = (w > M) ? w : M; sfx[b] = M; }
    }
    __syncthreads();
    if (tid < NB) {  // column prefix: scatter base per (block g, bucket tid)
        unsigned s = basev[tid];
        for (int g = 0; g < 64; ++g) {
            cbase[g * NB + tid] = s;
            s += hist[g * NB + tid];
        }
    }
    // per-tile bound: bucket containing position 64*tid, then suffix bucket max
    {
        const unsigned pos = (unsigned)tid * 64u;
        int b = 0;
        for (int bb = 0; bb < NB; ++bb)
            if (basev[bb] <= pos && pos < basev[bb + 1]) b = bb;
        const float B = __uint_as_float(sfx[b]);
        const float sqB_up = __uint_as_float(__float_as_uint(__fsqrt_rn(B)) + 2u);
        bnd[tid] = make_float2(B, sqB_up);
    }
}

// ---- prep 3: deterministic scatter (64 blocks, parallel) ----
__global__ __launch_bounds__(256) void k_scatter(const float* __restrict__ x,
                                                 const unsigned* __restrict__ cbase,
                                                 float4* __restrict__ tab,
                                                 unsigned* __restrict__ idxarr) {
    __shared__ unsigned c[NB];
    const int tid = threadIdx.x;
    if (tid < NB) c[tid] = 0u;
    __syncthreads();
    const int i = blockIdx.x * 256 + tid;
    const float gx = x[3 * i], gy = x[3 * i + 1], gz = x[3 * i + 2];
    const float sq = sq_of(gx, gy, gz);
    const int b = bucket_of(sq);
    const unsigned r = atomicAdd(&c[b], 1u);
    const unsigned pos = cbase[blockIdx.x * NB + b] + r;
    tab[pos] = make_float4(gx, gy, gz, -sq);
    idxarr[pos] = (unsigned)i;
}

// ---- main kernel: R11 verbatim ----
__global__ __launch_bounds__(256) void knn_far_kernel(
    const float* __restrict__ x, const float4* __restrict__ tab,
    const unsigned* __restrict__ idxarr, const float2* __restrict__ bnd,
    float* __restrict__ out_d, float* __restrict__ out_i) {
    __shared__ double swall[4 * 64];
    const int tid  = threadIdx.x;
    const int lane = tid & 63;
    const int wid  = tid >> 6;
    double* sw = swall + wid * 64;
    const int q0 = (blockIdx.x * 4 + wid) * 2;
    const int q1 = q0 + 1;

    const float a0 = x[3 * q0], a1 = x[3 * q0 + 1], a2 = x[3 * q0 + 2];
    const float b0 = x[3 * q1], b1 = x[3 * q1 + 1], b2 = x[3 * q1 + 2];
    const float sq0 = sq_of(a0, a1, a2), sq1 = sq_of(b0, b1, b2);
    const v2f nsq01 = {-sq0, -sq1};
    const v2f c0A = {2.0f * a0, 2.0f * b0};
    const v2f c1A = {2.0f * a1, 2.0f * b1};
    const v2f c2A = {2.0f * a2, 2.0f * b2};
    // upper-bounded 2*|q| for the certificate
    const float twor0 = 2.0f * __uint_as_float(__float_as_uint(__fsqrt_rn(sq0)) + 2u);
    const float twor1 = 2.0f * __uint_as_float(__float_as_uint(__fsqrt_rn(sq1)) + 2u);

    float T0, T1; unsigned J0, J1;
    float fF0, fF1, thr0, thr1;

    {   // tile 0: seed via wave-parallel presort (no insert flood)
        TILE_AT(0)
        presort64(d2[0], jvec, lane, sw, T0, J0);
        presort64(d2[1], jvec, lane, sw, T1, J1);
        fF0 = RL16(T0); thr0 = __fsub_rn(-fF0, MARGIN);
        fF1 = RL16(T1); thr1 = __fsub_rn(-fF1, MARGIN);
    }
#pragma unroll
    for (int t = 1; t < 4; ++t) {  // rest of the seed region (top-256 norms)
        TILE_AT(t)
        PROCESS_LOADED();
    }
    for (int t = 4; t < NTILES; ++t) {
        const float2 bd = bnd[t];  // B = max sq_p over positions >= 64t (bucket-granular)
        const float u0 = __builtin_fmaf(twor0, bd.y, __fadd_rn(sq0, bd.x));
        const float u1 = __builtin_fmaf(twor1, bd.y, __fadd_rn(sq1, bd.x));
        if (u0 < thr0 && u1 < thr1) break;  // certified: no future point can matter
        TILE_AT(t)
        PROCESS_LOADED();
    }

    if (lane >= 1 && lane <= KOUT) {  // ranks 1..16 (rank 0 dropped by reference)
        const int r = lane - 1;
        out_d[q0 * KOUT + r] = T0;
        out_i[q0 * KOUT + r] = (float)J0;
        out_d[q1 * KOUT + r] = T1;
        out_i[q1 * KOUT + r] = (float)J1;
    }
}

extern "C" void kernel_launch(void* const* d_in, const int* in_sizes, int n_in,
                              void* d_out, int out_size, void* d_ws, size_t ws_size,
                              hipStream_t stream) {
    const float* x = (const float*)d_in[0];
    char* ws = (char*)d_ws;
    float4*   tab    = (float4*)(ws + WS_TAB);
    unsigned* idxarr = (unsigned*)(ws + WS_IDX);
    float2*   bnd    = (float2*)(ws + WS_BND);
    unsigned* hist   = (unsigned*)(ws + WS_HIST);
    unsigned* hmax   = (unsigned*)(ws + WS_HMAX);
    unsigned* cbase  = (unsigned*)(ws + WS_CBASE);
    float* out_d = (float*)d_out;
    float* out_i = out_d + (size_t)BN * KOUT;

    hipLaunchKernelGGL(k_hist,    dim3(64), dim3(256), 0, stream, x, hist, hmax);
    hipLaunchKernelGGL(k_mid,     dim3(1),  dim3(256), 0, stream, hist, hmax, cbase, bnd);
    hipLaunchKernelGGL(k_scatter, dim3(64), dim3(256), 0, stream, x, cbase, tab, idxarr);
    hipLaunchKernelGGL(knn_far_kernel, dim3(BN / 8), dim3(256), 0, stream,
                       x, tab, idxarr, bnd, out_d, out_i);
}